// Round 3
// baseline (1572.785 us; speedup 1.0000x reference)
//
#include <hip/hip_runtime.h>
#include <hip/hip_bf16.h>
#include <cstddef>
#include <cstdint>

typedef __attribute__((ext_vector_type(8))) short v8s;     // 8 bf16 (4 VGPR)
typedef __attribute__((ext_vector_type(16))) float v16f;   // MFMA 32x32 acc

#define GLDS(SRC, DST) __builtin_amdgcn_global_load_lds( \
    (const __attribute__((address_space(1))) void*)(SRC), \
    (__attribute__((address_space(3))) void*)(DST), 16, 0, 0)

// RNE fp32 -> bf16 split: x ~= hi + lo, |x - hi - lo| <~ 2^-18 |x|
__device__ __forceinline__ void bf16split(float x, unsigned short& h, unsigned short& l) {
    union { float f; unsigned u; } a; a.f = x;
    unsigned r = a.u + 0x7fff + ((a.u >> 16) & 1);
    h = (unsigned short)(r >> 16);
    union { unsigned u; float f; } hb; hb.u = (unsigned)h << 16;
    union { float f; unsigned u; } b; b.f = x - hb.f;
    unsigned r2 = b.u + 0x7fff + ((b.u >> 16) & 1);
    l = (unsigned short)(r2 >> 16);
}

// ---------------------------------------------------------------------------
// prep: wT1[k*256+oc] = conv1_w[oc*81+k]  (fp32, for conv1)
//       wpk: primary weights, bf16 hi/lo split, pre-swizzled for LDS:
//       region (chunk,k): 256 rows (ch) x 256 B; row ch logical byte
//       v = half*128 + icl*2 stored at v ^ ((ch&15)<<4).
// ---------------------------------------------------------------------------
__global__ __launch_bounds__(256) void prep_kernel(
    const float* __restrict__ cw, const float* __restrict__ pw,
    float* __restrict__ wT1, char* __restrict__ wpk)
{
    int idx = blockIdx.x * 256 + threadIdx.x;
    if (idx < 81 * 256) {
        int k = idx >> 8, oc = idx & 255;
        wT1[idx] = cw[oc * 81 + k];
    }
    int icl = idx & 63;
    int t = idx >> 6;
    int ch = t & 255; t >>= 8;          // t in [0, 324)
    int k = t % 81, chunk = t / 81;
    int ic = chunk * 64 + icl;
    float wv = pw[((ch << 8) + ic) * 81 + k];
    unsigned short h, l; bf16split(wv, h, l);
    size_t rowb = ((size_t)(chunk * 81 + k) * 256 + ch) * 256;
    int sw = (ch & 15) << 4;
    *(unsigned short*)(wpk + rowb + ((icl * 2) ^ sw)) = h;
    *(unsigned short*)(wpk + rowb + ((128 + icl * 2) ^ sw)) = l;
}

// ---------------------------------------------------------------------------
// conv1: [B,1,28,28] -> xc2 rows [bc*400] of 1024 B: [hi 256 bf16][lo 256 bf16]
// ---------------------------------------------------------------------------
__global__ __launch_bounds__(256) void conv1_kernel(
    const float* __restrict__ img,   // [B][784]
    const float* __restrict__ wT1,   // [81][256]
    const float* __restrict__ bias,  // [256]
    char* __restrict__ xc2,          // [bc][400][1024 B]
    int b0)
{
    const int bl = blockIdx.x;
    const int oc = threadIdx.x;
    __shared__ float im[784];
    const float* ib = img + (size_t)(b0 + bl) * 784;
    for (int e = oc; e < 784; e += 256) im[e] = ib[e];
    float w[81];
#pragma unroll
    for (int k = 0; k < 81; ++k) w[k] = wT1[k * 256 + oc];
    float bv = bias[oc];
    __syncthreads();
    char* ob = xc2 + (size_t)bl * 409600;
    for (int oy = 0; oy < 20; ++oy) {
        for (int ox = 0; ox < 20; ++ox) {
            float a = bv;
#pragma unroll
            for (int ky = 0; ky < 9; ++ky)
#pragma unroll
                for (int kx = 0; kx < 9; ++kx)
                    a = fmaf(w[ky * 9 + kx], im[(oy + ky) * 28 + ox + kx], a);
            a = fmaxf(a, 0.f);
            unsigned short h, l; bf16split(a, h, l);
            char* rp = ob + (size_t)(oy * 20 + ox) * 1024;
            *(unsigned short*)(rp + oc * 2) = h;
            *(unsigned short*)(rp + 512 + oc * 2) = l;
        }
    }
}

// ---------------------------------------------------------------------------
// primary conv implicit GEMM, split-bf16 (3 products). Grid 1D = Mtiles*8:
// id&7 -> (g = chunk, nh = channel half) so each of the 8 XCDs keeps one
// (g,nh) B-panel (2.6 MB) resident in its L2. Block: 128 thr = 2 waves,
// BM=128 x BN=128, wave tile 64x128 (2x4 frags of 32x32x16).
// LDS: A 32 KB (gathered rows, src-swizzled), B 32 KB (linear, pre-swizzled).
// ---------------------------------------------------------------------------
__global__ __launch_bounds__(128, 1) void gemm_kernel(
    const char* __restrict__ xc2,   // [bc][400][1024 B]
    const char* __restrict__ wpk,   // [4][81][256][256 B] pre-swizzled
    float* __restrict__ part,       // [4][M][256]
    int bc)
{
    __shared__ __align__(128) char As[128 * 256];   // 32 KB
    __shared__ __align__(128) char Bs[128 * 256];   // 32 KB
    const int tid = threadIdx.x;
    const int w2 = tid >> 6, lane = tid & 63;
    const int id = blockIdx.x;
    const int g = (id & 7) >> 1;             // ic chunk 0..3
    const int n0 = (id & 1) << 7;            // channel half 0/128
    const int m0 = (id >> 3) * 128;
    const int M = bc * 36;

    // Per-lane A-gather constants (16 issues of 1 KB per wave)
    int pbase[16], soff[16];
#pragma unroll
    for (int i = 0; i < 16; ++i) {
        int d = (w2 * 16 + i) * 1024 + lane * 16;
        int r = d >> 8;                      // LDS row = m - m0
        int v = (d & 255) ^ ((r & 15) << 4); // logical byte in 256-B row
        soff[i] = (v < 128) ? (g * 128 + v) : (512 + g * 128 + (v - 128));
        int m = m0 + r; if (m >= M) m = M - 1;
        int b = m / 36, s = m - b * 36;
        pbase[i] = b * 400 + (s / 6) * 40 + (s % 6) * 2;
    }

    v16f acc[2][4];
#pragma unroll
    for (int i = 0; i < 2; ++i)
#pragma unroll
        for (int j = 0; j < 4; ++j)
#pragma unroll
            for (int e = 0; e < 16; ++e) acc[i][j][e] = 0.f;

    const char* wg = wpk + (size_t)g * 81 * 65536 + (size_t)n0 * 256;
    const int col = lane & 31, kg = lane >> 5;

    for (int k = 0; k < 81; ++k) {
        __syncthreads();                    // previous tile consumed
        const int koff = (k / 9) * 20 + (k % 9);
#pragma unroll
        for (int i = 0; i < 16; ++i)
            GLDS(xc2 + (size_t)(pbase[i] + koff) * 1024 + soff[i],
                 As + (w2 * 16 + i) * 1024);
        const char* bsrc = wg + (size_t)k * 65536 + (w2 * 16) * 1024 + lane * 16;
#pragma unroll
        for (int i = 0; i < 16; ++i)
            GLDS(bsrc + i * 1024, Bs + (w2 * 16 + i) * 1024);
        __syncthreads();                    // drains vmcnt

#pragma unroll
        for (int s = 0; s < 4; ++s) {
            const int vb = s * 32 + kg * 16;   // hi-plane byte base (16 B)
            v8s Ah[2], Al[2], Bh[4], Bl[4];
#pragma unroll
            for (int fm = 0; fm < 2; ++fm) {
                int r = w2 * 64 + fm * 32 + col;
                int sw = (r & 15) << 4;
                Ah[fm] = *(const v8s*)(As + r * 256 + (vb ^ sw));
                Al[fm] = *(const v8s*)(As + r * 256 + ((128 + vb) ^ sw));
            }
#pragma unroll
            for (int fn = 0; fn < 4; ++fn) {
                int cr = fn * 32 + col;
                int sw = (cr & 15) << 4;
                Bh[fn] = *(const v8s*)(Bs + cr * 256 + (vb ^ sw));
                Bl[fn] = *(const v8s*)(Bs + cr * 256 + ((128 + vb) ^ sw));
            }
#pragma unroll
            for (int fm = 0; fm < 2; ++fm)
#pragma unroll
                for (int fn = 0; fn < 4; ++fn) {
                    acc[fm][fn] = __builtin_amdgcn_mfma_f32_32x32x16_bf16(Al[fm], Bh[fn], acc[fm][fn], 0, 0, 0);
                    acc[fm][fn] = __builtin_amdgcn_mfma_f32_32x32x16_bf16(Ah[fm], Bl[fn], acc[fm][fn], 0, 0, 0);
                    acc[fm][fn] = __builtin_amdgcn_mfma_f32_32x32x16_bf16(Ah[fm], Bh[fn], acc[fm][fn], 0, 0, 0);
                }
        }
    }

    // store C partials: part[g][m][ch]
    float* pg = part + (size_t)g * M * 256;
    const bool full = (m0 + 128 <= M);
#pragma unroll
    for (int fm = 0; fm < 2; ++fm)
#pragma unroll
        for (int fn = 0; fn < 4; ++fn) {
            int ch = n0 + fn * 32 + col;
#pragma unroll
            for (int rg = 0; rg < 16; ++rg) {
                int row = (rg & 3) + 8 * (rg >> 2) + 4 * kg;
                int m = m0 + w2 * 64 + fm * 32 + row;
                if (full || m < M) pg[(size_t)m * 256 + ch] = acc[fm][fn][rg];
            }
        }
}

// ---------------------------------------------------------------------------
// partials -> +bias -> regroup -> squash -> u [B][1152][8]
// ---------------------------------------------------------------------------
__global__ __launch_bounds__(256) void prim2u_kernel(
    const float* __restrict__ part, const float* __restrict__ pb,
    float* __restrict__ u, int bc, int b0)
{
    int i = blockIdx.x * 256 + threadIdx.x;
    if (i >= bc * 1152) return;
    int bl = i / 1152, n = i - bl * 1152;
    int cc = n / 36, s = n - cc * 36;
    int m = bl * 36 + s;
    int M = bc * 36;
    float p8[8]; float sn = 0.f;
#pragma unroll
    for (int d = 0; d < 8; ++d) {
        int ch = d * 32 + cc;
        float v = pb[ch];
#pragma unroll
        for (int g = 0; g < 4; ++g) v += part[((size_t)g * M + m) * 256 + ch];
        p8[d] = v; sn += v * v;
    }
    float fac = sqrtf(sn) / (1.0f + sn);
    float4 o0, o1;
    o0.x = fac * p8[0]; o0.y = fac * p8[1]; o0.z = fac * p8[2]; o0.w = fac * p8[3];
    o1.x = fac * p8[4]; o1.y = fac * p8[5]; o1.z = fac * p8[6]; o1.w = fac * p8[7];
    float* up = u + ((size_t)(b0 + bl) * 1152 + n) * 8;
    *(float4*)up = o0;
    *(float4*)(up + 4) = o1;
}

// ---------------------------------------------------------------------------
// routing: one block per (b-pair, c), 512 thr. u_hat for BOTH images in LDS
// (147 KB): W row read once, used for 2 images -> W traffic halved.
// Waves 0-3 route image 0, waves 4-7 image 1 (identical barrier sequence).
// ---------------------------------------------------------------------------
__global__ __launch_bounds__(512) void routing_kernel(
    const float* __restrict__ u,   // [B][1152][8]
    const float* __restrict__ W,   // [10][1152][8][16]
    float* __restrict__ out,       // [B][10][16]
    int B)
{
    const int b0 = blockIdx.x * 2;
    const int c = blockIdx.y;
    const int tid = threadIdx.x;
    __shared__ float uh[2][1152][16];     // 147456 B
    __shared__ float bijs[2][1152];       // 9216 B
    __shared__ float red[2][4 * 17];
    __shared__ float sred[2][17];
    __shared__ float mred[2][4];

    const float* __restrict__ Wc = W + (size_t)c * (1152 * 128);
    const int b1 = (b0 + 1 < B) ? b0 + 1 : b0;
    const float* __restrict__ ub0 = u + (size_t)b0 * 9216;
    const float* __restrict__ ub1 = u + (size_t)b1 * 9216;

    for (int n = tid; n < 1152; n += 512) {
        const float4* p0 = (const float4*)(ub0 + n * 8);
        const float4* p1 = (const float4*)(ub1 + n * 8);
        float4 a0 = p0[0], a1 = p0[1], b0v = p1[0], b1v = p1[1];
        float uu0[8] = {a0.x, a0.y, a0.z, a0.w, a1.x, a1.y, a1.z, a1.w};
        float uu1[8] = {b0v.x, b0v.y, b0v.z, b0v.w, b1v.x, b1v.y, b1v.z, b1v.w};
        float acc0[16], acc1[16];
#pragma unroll
        for (int o = 0; o < 16; ++o) { acc0[o] = 0.f; acc1[o] = 0.f; }
        const float* wn = Wc + n * 128;
#pragma unroll
        for (int i = 0; i < 8; ++i)
#pragma unroll
            for (int o = 0; o < 16; ++o) {
                float wv = wn[i * 16 + o];
                acc0[o] = fmaf(uu0[i], wv, acc0[o]);
                acc1[o] = fmaf(uu1[i], wv, acc1[o]);
            }
#pragma unroll
        for (int o = 0; o < 16; ++o) { uh[0][n][o] = acc0[o]; uh[1][n][o] = acc1[o]; }
        bijs[0][n] = 0.f; bijs[1][n] = 0.f;
    }
    __syncthreads();

    const int img = tid >> 8, t = tid & 255;
    const int wid = t >> 6, lane = t & 63;
    float (* __restrict__ UH)[16] = uh[img];
    float* __restrict__ bij = bijs[img];
    float* __restrict__ redi = red[img];
    float* __restrict__ sredi = sred[img];
    float* __restrict__ mredi = mred[img];

    float v[16];
    float fac = 0.f, inv = 0.f;
    for (int it = 0; it < 3; ++it) {
        float m = -3.4e38f;
        for (int n = t; n < 1152; n += 256) m = fmaxf(m, bij[n]);
#pragma unroll
        for (int off = 32; off > 0; off >>= 1) m = fmaxf(m, __shfl_down(m, off));
        if (lane == 0) mredi[wid] = m;
        __syncthreads();
        float M = fmaxf(fmaxf(mredi[0], mredi[1]), fmaxf(mredi[2], mredi[3]));
        float se = 0.f;
        float sp[16];
#pragma unroll
        for (int o = 0; o < 16; ++o) sp[o] = 0.f;
        for (int n = t; n < 1152; n += 256) {
            float e = expf(bij[n] - M);
            se += e;
#pragma unroll
            for (int o = 0; o < 16; ++o) sp[o] = fmaf(e, UH[n][o], sp[o]);
        }
#pragma unroll
        for (int o = 0; o < 16; ++o)
#pragma unroll
            for (int off = 32; off > 0; off >>= 1) sp[o] += __shfl_down(sp[o], off);
#pragma unroll
        for (int off = 32; off > 0; off >>= 1) se += __shfl_down(se, off);
        if (lane == 0) {
#pragma unroll
            for (int o = 0; o < 16; ++o) redi[wid * 17 + o] = sp[o];
            redi[wid * 17 + 16] = se;
        }
        __syncthreads();
        if (t < 17)
            sredi[t] = redi[t] + redi[17 + t] + redi[34 + t] + redi[51 + t];
        __syncthreads();
        inv = 1.0f / sredi[16];
        float sn = 0.f;
        float sj[16];
#pragma unroll
        for (int o = 0; o < 16; ++o) { sj[o] = sredi[o] * inv; sn = fmaf(sj[o], sj[o], sn); }
        fac = sqrtf(sn) / (1.0f + sn);
#pragma unroll
        for (int o = 0; o < 16; ++o) v[o] = fac * sj[o];
        if (it < 2) {
            for (int n = t; n < 1152; n += 256) {
                float a = 0.f;
#pragma unroll
                for (int o = 0; o < 16; ++o) a = fmaf(UH[n][o], v[o], a);
                bij[n] += a;
            }
        }
        __syncthreads();
    }
    if (t < 16 && b0 + img < B)
        out[((size_t)(b0 + img) * 10 + c) * 16 + t] = fac * (sredi[t] * inv);
}

// ---------------------------------------------------------------------------
extern "C" void kernel_launch(void* const* d_in, const int* in_sizes, int n_in,
                              void* d_out, int out_size, void* d_ws, size_t ws_size,
                              hipStream_t stream) {
    const float* images  = (const float*)d_in[0];
    const float* conv1_w = (const float*)d_in[1];
    const float* conv1_b = (const float*)d_in[2];
    const float* prim_w  = (const float*)d_in[3];
    const float* prim_b  = (const float*)d_in[4];
    const float* W       = (const float*)d_in[5];
    float* out = (float*)d_out;

    const int B = in_sizes[0] / 784;

    char* wsb = (char*)d_ws;
    float* u = (float*)wsb;
    size_t off = (size_t)B * 1152 * 8 * 4;
    float* wT1 = (float*)(wsb + off);
    off += 81 * 256 * 4;
    off = (off + 1023) & ~(size_t)1023;
    char* wpk = wsb + off;
    off += (size_t)4 * 81 * 256 * 256;          // 21.2 MB
    size_t rem = (ws_size > off) ? ws_size - off : 0;
    const size_t perimg = 409600 + 147456;       // xc2 + partials
    int Bc = (int)(rem / perimg);
    if (Bc > B) Bc = B;
    if (Bc >= 32) Bc &= ~31;                     // multiple of 32 -> exact 128-tiles
    if (Bc < 1) Bc = 1;

    prep_kernel<<<20736, 256, 0, stream>>>(conv1_w, prim_w, wT1, wpk);

    for (int b0 = 0; b0 < B; b0 += Bc) {
        int bc = (B - b0 < Bc) ? (B - b0) : Bc;
        char* xc2 = wsb + off;
        float* part = (float*)(xc2 + (size_t)Bc * 409600);
        conv1_kernel<<<bc, 256, 0, stream>>>(images, wT1, conv1_b, xc2, b0);
        int Mtiles = (bc * 36 + 127) / 128;
        gemm_kernel<<<Mtiles * 8, 128, 0, stream>>>(xc2, wpk, part, bc);
        int items = bc * 1152;
        prim2u_kernel<<<(items + 255) / 256, 256, 0, stream>>>(part, prim_b, u, bc, b0);
    }
    dim3 rg((B + 1) / 2, 10);
    routing_kernel<<<rg, 512, 0, stream>>>(u, W, out, B);
}

// Round 4
// 1455.122 us; speedup vs baseline: 1.0809x; 1.0809x over previous
//
#include <hip/hip_runtime.h>
#include <hip/hip_bf16.h>
#include <cstddef>
#include <cstdint>

typedef __attribute__((ext_vector_type(8))) short v8s;     // 8 bf16 (4 VGPR)
typedef __attribute__((ext_vector_type(16))) float v16f;   // MFMA 32x32 acc

#define GLDS(SRC, DST) __builtin_amdgcn_global_load_lds( \
    (const __attribute__((address_space(1))) void*)(SRC), \
    (__attribute__((address_space(3))) void*)(DST), 16, 0, 0)

// RNE fp32 -> bf16 split: x ~= hi + lo, |x - hi - lo| <~ 2^-18 |x|
__device__ __forceinline__ void bf16split(float x, unsigned short& h, unsigned short& l) {
    union { float f; unsigned u; } a; a.f = x;
    unsigned r = a.u + 0x7fff + ((a.u >> 16) & 1);
    h = (unsigned short)(r >> 16);
    union { unsigned u; float f; } hb; hb.u = (unsigned)h << 16;
    union { float f; unsigned u; } b; b.f = x - hb.f;
    unsigned r2 = b.u + 0x7fff + ((b.u >> 16) & 1);
    l = (unsigned short)(r2 >> 16);
}

// ---------------------------------------------------------------------------
// prep: wT1[k*256+oc] = conv1_w[oc*81+k]  (fp32, for conv1)
//       wpk slabs: (g' 0..7, k 0..80) of 32 KB = 128 rows x 256 B.
//       row r, logical byte v: ch = r + 128*(v>>7), plane = (v>>6)&1 (hi/lo),
//       ic = g'*32 + (v&63)/2.  Stored at v ^ ((r&15)<<4)  (16-slot XOR).
// grid 2592 x 256: idx -> (slab 648)(r 128)(chsel 2)(q 4); thread = 8 ic.
// ---------------------------------------------------------------------------
__global__ __launch_bounds__(256) void prep_kernel(
    const float* __restrict__ cw, const float* __restrict__ pw,
    float* __restrict__ wT1, char* __restrict__ wpk)
{
    int idx = blockIdx.x * 256 + threadIdx.x;
    if (idx < 81 * 256) {
        int k = idx >> 8, oc = idx & 255;
        wT1[idx] = cw[oc * 81 + k];
    }
    int q = idx & 3; idx >>= 2;
    int chsel = idx & 1; idx >>= 1;
    int r = idx & 127; idx >>= 7;
    int slab = idx;                       // 0..647
    int gp = slab / 81, k = slab - gp * 81;
    int ch = r + 128 * chsel;
    const float* pwp = pw + ((size_t)(ch * 256) + gp * 32 + q * 8) * 81 + k;
    v8s hv, lv;
#pragma unroll
    for (int j = 0; j < 8; ++j) {
        unsigned short h, l; bf16split(pwp[(size_t)j * 81], h, l);
        hv[j] = (short)h; lv[j] = (short)l;
    }
    char* rowb = wpk + (size_t)slab * 32768 + r * 256;
    int sw = (r & 15) << 4;
    int vhi = chsel * 128 + q * 16;
    *(v8s*)(rowb + (vhi ^ sw)) = hv;
    *(v8s*)(rowb + ((vhi + 64) ^ sw)) = lv;
}

// ---------------------------------------------------------------------------
// conv1: [B,1,28,28] -> xc2 rows [bc*400] of 1024 B: [hi 256 bf16][lo 256 bf16]
// ---------------------------------------------------------------------------
__global__ __launch_bounds__(256) void conv1_kernel(
    const float* __restrict__ img,   // [B][784]
    const float* __restrict__ wT1,   // [81][256]
    const float* __restrict__ bias,  // [256]
    char* __restrict__ xc2,          // [bc][400][1024 B]
    int b0)
{
    const int bl = blockIdx.x;
    const int oc = threadIdx.x;
    __shared__ float im[784];
    const float* ib = img + (size_t)(b0 + bl) * 784;
    for (int e = oc; e < 784; e += 256) im[e] = ib[e];
    float w[81];
#pragma unroll
    for (int k = 0; k < 81; ++k) w[k] = wT1[k * 256 + oc];
    float bv = bias[oc];
    __syncthreads();
    char* ob = xc2 + (size_t)bl * 409600;
    for (int oy = 0; oy < 20; ++oy) {
        for (int ox = 0; ox < 20; ++ox) {
            float a = bv;
#pragma unroll
            for (int ky = 0; ky < 9; ++ky)
#pragma unroll
                for (int kx = 0; kx < 9; ++kx)
                    a = fmaf(w[ky * 9 + kx], im[(oy + ky) * 28 + ox + kx], a);
            a = fmaxf(a, 0.f);
            unsigned short h, l; bf16split(a, h, l);
            char* rp = ob + (size_t)(oy * 20 + ox) * 1024;
            *(unsigned short*)(rp + oc * 2) = h;
            *(unsigned short*)(rp + 512 + oc * 2) = l;
        }
    }
}

// ---------------------------------------------------------------------------
// primary conv implicit GEMM, split-bf16 (3 products), split-K x4 over ic
// chunks (g = id&3). BM=64 x BN=256, 4 waves, wave-tile 64x64.
// 2-phase pipelined double-buffer: per step (k-pos x 32-ic sub-chunk) stage
// A 8 KB + B 32 KB into buf^1 while computing buf.  162 steps.
// A LDS: 32 rows x 256 B (row r = m-rows r / r+32).  B: 128 rows x 256 B
// (row r = ch r / r+128).  Both 16-slot XOR swizzled; A gathered with
// inverse-swizzled per-lane source, B linear from pre-swizzled wpk.
// ---------------------------------------------------------------------------
__global__ __launch_bounds__(256, 2) void gemm_kernel(
    const char* __restrict__ xc2,   // [bc][400][1024 B]
    const char* __restrict__ wpk,   // [648 slabs][32 KB]
    float* __restrict__ part,       // [4][M][256]
    int bc)
{
    __shared__ __align__(128) char As[2][8192];
    __shared__ __align__(128) char Bs[2][32768];
    const int tid = threadIdx.x;
    const int w2 = tid >> 6, lane = tid & 63;
    const int id = blockIdx.x;
    const int g = id & 3;
    const int m0 = (id >> 2) * 64;
    const int M = bc * 36;

    // A-gather per-lane constants (2 issues of 1 KB per wave)
    int pbaseA[2], srcA[2];
#pragma unroll
    for (int i = 0; i < 2; ++i) {
        int d = w2 * 2048 + i * 1024 + lane * 16;
        int r = d >> 8, dv = d & 255;
        int v = dv ^ ((r & 15) << 4);
        int m = r + ((v >> 7) << 5);
        int v7 = v & 127;
        int mg = m0 + m; if (mg >= M) mg = M - 1;
        int b = mg / 36, s = mg - b * 36;
        pbaseA[i] = b * 400 + (s / 6) * 40 + (s % 6) * 2;
        srcA[i] = ((v7 & 64) ? 512 : 0) + g * 128 + (v7 & 63);
    }
    const char* wg = wpk + (size_t)(g * 2) * 81 * 32768;   // slabs g'=2g..2g+1

    v16f acc[2][2];
#pragma unroll
    for (int i = 0; i < 2; ++i)
#pragma unroll
        for (int j = 0; j < 2; ++j)
#pragma unroll
            for (int e = 0; e < 16; ++e) acc[i][j][e] = 0.f;

    const int col = lane & 31, kg = lane >> 5;
    const int sw = (col & 15) << 4;

    // prologue: stage step 0 (k=0, sub=0, koff=0)
#pragma unroll
    for (int i = 0; i < 2; ++i)
        GLDS(xc2 + (size_t)pbaseA[i] * 1024 + srcA[i], &As[0][w2 * 2048 + i * 1024]);
#pragma unroll
    for (int i = 0; i < 8; ++i)
        GLDS(wg + i * 4096 + tid * 16, &Bs[0][i * 4096 + w2 * 1024]);
    __syncthreads();

    for (int t = 0; t < 162; ++t) {
        const int cur = t & 1;
        const char* Ab = &As[cur][0];
        const char* Bb = &Bs[cur][0];
        if (t < 161) {
            const int tn = t + 1;
            const int kn = tn >> 1, subn = tn & 1;
            const int koff = (kn / 9) * 20 + (kn % 9);
            const int sO = subn * 64;
#pragma unroll
            for (int i = 0; i < 2; ++i)
                GLDS(xc2 + (size_t)(pbaseA[i] + koff) * 1024 + srcA[i] + sO,
                     &As[cur ^ 1][w2 * 2048 + i * 1024]);
            const char* bs = wg + (size_t)(subn * 81 + kn) * 32768;
#pragma unroll
            for (int i = 0; i < 8; ++i)
                GLDS(bs + i * 4096 + tid * 16, &Bs[cur ^ 1][i * 4096 + w2 * 1024]);
        }
#pragma unroll
        for (int s = 0; s < 2; ++s) {
            const int vb = s * 32 + kg * 16;
            v8s Ah[2], Al[2];
#pragma unroll
            for (int fm = 0; fm < 2; ++fm) {
                Ah[fm] = *(const v8s*)(Ab + col * 256 + ((fm * 128 + vb) ^ sw));
                Al[fm] = *(const v8s*)(Ab + col * 256 + ((fm * 128 + 64 + vb) ^ sw));
            }
#pragma unroll
            for (int fn = 0; fn < 2; ++fn) {
                int ch = w2 * 64 + fn * 32 + col;
                int rr = ch & 127;
                int base = (ch >> 7) << 7;
                v8s Bh = *(const v8s*)(Bb + rr * 256 + ((base + vb) ^ sw));
                v8s Bl = *(const v8s*)(Bb + rr * 256 + ((base + 64 + vb) ^ sw));
#pragma unroll
                for (int fm = 0; fm < 2; ++fm) {
                    acc[fm][fn] = __builtin_amdgcn_mfma_f32_32x32x16_bf16(Al[fm], Bh, acc[fm][fn], 0, 0, 0);
                    acc[fm][fn] = __builtin_amdgcn_mfma_f32_32x32x16_bf16(Ah[fm], Bl, acc[fm][fn], 0, 0, 0);
                    acc[fm][fn] = __builtin_amdgcn_mfma_f32_32x32x16_bf16(Ah[fm], Bh, acc[fm][fn], 0, 0, 0);
                }
            }
        }
        __syncthreads();
    }

    // store C partials: part[g][m][ch]
    float* pg = part + (size_t)g * M * 256;
    const bool full = (m0 + 64 <= M);
#pragma unroll
    for (int fm = 0; fm < 2; ++fm)
#pragma unroll
        for (int fn = 0; fn < 2; ++fn) {
            int ch = w2 * 64 + fn * 32 + col;
#pragma unroll
            for (int rg = 0; rg < 16; ++rg) {
                int row = (rg & 3) + 8 * (rg >> 2) + 4 * kg;
                int m = m0 + fm * 32 + row;
                if (full || m < M) pg[(size_t)m * 256 + ch] = acc[fm][fn][rg];
            }
        }
}

// ---------------------------------------------------------------------------
// partials -> +bias -> regroup -> squash -> u [B][1152][8]
// ---------------------------------------------------------------------------
__global__ __launch_bounds__(256) void prim2u_kernel(
    const float* __restrict__ part, const float* __restrict__ pb,
    float* __restrict__ u, int bc, int b0)
{
    int i = blockIdx.x * 256 + threadIdx.x;
    if (i >= bc * 1152) return;
    int bl = i / 1152, n = i - bl * 1152;
    int cc = n / 36, s = n - cc * 36;
    int m = bl * 36 + s;
    int M = bc * 36;
    float p8[8]; float sn = 0.f;
#pragma unroll
    for (int d = 0; d < 8; ++d) {
        int ch = d * 32 + cc;
        float v = pb[ch];
#pragma unroll
        for (int g = 0; g < 4; ++g) v += part[((size_t)g * M + m) * 256 + ch];
        p8[d] = v; sn += v * v;
    }
    float fac = sqrtf(sn) / (1.0f + sn);
    float4 o0, o1;
    o0.x = fac * p8[0]; o0.y = fac * p8[1]; o0.z = fac * p8[2]; o0.w = fac * p8[3];
    o1.x = fac * p8[4]; o1.y = fac * p8[5]; o1.z = fac * p8[6]; o1.w = fac * p8[7];
    float* up = u + ((size_t)(b0 + bl) * 1152 + n) * 8;
    *(float4*)up = o0;
    *(float4*)(up + 4) = o1;
}

// ---------------------------------------------------------------------------
// routing: one block per (b-pair, c), 512 thr. u_hat for BOTH images in LDS:
// W row read once, used for 2 images. Waves 0-3 image 0, waves 4-7 image 1.
// ---------------------------------------------------------------------------
__global__ __launch_bounds__(512) void routing_kernel(
    const float* __restrict__ u,   // [B][1152][8]
    const float* __restrict__ W,   // [10][1152][8][16]
    float* __restrict__ out,       // [B][10][16]
    int B)
{
    const int b0 = blockIdx.x * 2;
    const int c = blockIdx.y;
    const int tid = threadIdx.x;
    __shared__ float uh[2][1152][16];
    __shared__ float bijs[2][1152];
    __shared__ float red[2][4 * 17];
    __shared__ float sred[2][17];
    __shared__ float mred[2][4];

    const float* __restrict__ Wc = W + (size_t)c * (1152 * 128);
    const int b1 = (b0 + 1 < B) ? b0 + 1 : b0;
    const float* __restrict__ ub0 = u + (size_t)b0 * 9216;
    const float* __restrict__ ub1 = u + (size_t)b1 * 9216;

    for (int n = tid; n < 1152; n += 512) {
        const float4* p0 = (const float4*)(ub0 + n * 8);
        const float4* p1 = (const float4*)(ub1 + n * 8);
        float4 a0 = p0[0], a1 = p0[1], c0 = p1[0], c1 = p1[1];
        float uu0[8] = {a0.x, a0.y, a0.z, a0.w, a1.x, a1.y, a1.z, a1.w};
        float uu1[8] = {c0.x, c0.y, c0.z, c0.w, c1.x, c1.y, c1.z, c1.w};
        float acc0[16], acc1[16];
#pragma unroll
        for (int o = 0; o < 16; ++o) { acc0[o] = 0.f; acc1[o] = 0.f; }
        const float* wn = Wc + n * 128;
#pragma unroll
        for (int i = 0; i < 8; ++i)
#pragma unroll
            for (int o = 0; o < 16; ++o) {
                float wv = wn[i * 16 + o];
                acc0[o] = fmaf(uu0[i], wv, acc0[o]);
                acc1[o] = fmaf(uu1[i], wv, acc1[o]);
            }
#pragma unroll
        for (int o = 0; o < 16; ++o) { uh[0][n][o] = acc0[o]; uh[1][n][o] = acc1[o]; }
        bijs[0][n] = 0.f; bijs[1][n] = 0.f;
    }
    __syncthreads();

    const int img = tid >> 8, t = tid & 255;
    const int wid = t >> 6, lane = t & 63;
    float (* __restrict__ UH)[16] = uh[img];
    float* __restrict__ bij = bijs[img];
    float* __restrict__ redi = red[img];
    float* __restrict__ sredi = sred[img];
    float* __restrict__ mredi = mred[img];

    float v[16];
    float fac = 0.f, inv = 0.f;
    for (int it = 0; it < 3; ++it) {
        float m = -3.4e38f;
        for (int n = t; n < 1152; n += 256) m = fmaxf(m, bij[n]);
#pragma unroll
        for (int off = 32; off > 0; off >>= 1) m = fmaxf(m, __shfl_down(m, off));
        if (lane == 0) mredi[wid] = m;
        __syncthreads();
        float M = fmaxf(fmaxf(mredi[0], mredi[1]), fmaxf(mredi[2], mredi[3]));
        float se = 0.f;
        float sp[16];
#pragma unroll
        for (int o = 0; o < 16; ++o) sp[o] = 0.f;
        for (int n = t; n < 1152; n += 256) {
            float e = expf(bij[n] - M);
            se += e;
#pragma unroll
            for (int o = 0; o < 16; ++o) sp[o] = fmaf(e, UH[n][o], sp[o]);
        }
#pragma unroll
        for (int o = 0; o < 16; ++o)
#pragma unroll
            for (int off = 32; off > 0; off >>= 1) sp[o] += __shfl_down(sp[o], off);
#pragma unroll
        for (int off = 32; off > 0; off >>= 1) se += __shfl_down(se, off);
        if (lane == 0) {
#pragma unroll
            for (int o = 0; o < 16; ++o) redi[wid * 17 + o] = sp[o];
            redi[wid * 17 + 16] = se;
        }
        __syncthreads();
        if (t < 17)
            sredi[t] = redi[t] + redi[17 + t] + redi[34 + t] + redi[51 + t];
        __syncthreads();
        inv = 1.0f / sredi[16];
        float sn = 0.f;
        float sj[16];
#pragma unroll
        for (int o = 0; o < 16; ++o) { sj[o] = sredi[o] * inv; sn = fmaf(sj[o], sj[o], sn); }
        fac = sqrtf(sn) / (1.0f + sn);
#pragma unroll
        for (int o = 0; o < 16; ++o) v[o] = fac * sj[o];
        if (it < 2) {
            for (int n = t; n < 1152; n += 256) {
                float a = 0.f;
#pragma unroll
                for (int o = 0; o < 16; ++o) a = fmaf(UH[n][o], v[o], a);
                bij[n] += a;
            }
        }
        __syncthreads();
    }
    if (t < 16 && b0 + img < B)
        out[((size_t)(b0 + img) * 10 + c) * 16 + t] = fac * (sredi[t] * inv);
}

// ---------------------------------------------------------------------------
extern "C" void kernel_launch(void* const* d_in, const int* in_sizes, int n_in,
                              void* d_out, int out_size, void* d_ws, size_t ws_size,
                              hipStream_t stream) {
    const float* images  = (const float*)d_in[0];
    const float* conv1_w = (const float*)d_in[1];
    const float* conv1_b = (const float*)d_in[2];
    const float* prim_w  = (const float*)d_in[3];
    const float* prim_b  = (const float*)d_in[4];
    const float* W       = (const float*)d_in[5];
    float* out = (float*)d_out;

    const int B = in_sizes[0] / 784;

    char* wsb = (char*)d_ws;
    float* u = (float*)wsb;
    size_t off = (size_t)B * 1152 * 8 * 4;
    float* wT1 = (float*)(wsb + off);
    off += 81 * 256 * 4;
    off = (off + 1023) & ~(size_t)1023;
    char* wpk = wsb + off;
    off += (size_t)648 * 32768;                 // 21.2 MB
    size_t rem = (ws_size > off) ? ws_size - off : 0;
    const size_t perimg = 409600 + 147456;       // xc2 + partials
    int Bc = (int)(rem / perimg);
    if (Bc > B) Bc = B;
    if (Bc >= 16) Bc &= ~15;                     // multiple of 16 -> exact 64-tiles
    if (Bc < 1) Bc = 1;

    prep_kernel<<<2592, 256, 0, stream>>>(conv1_w, prim_w, wT1, wpk);

    for (int b0 = 0; b0 < B; b0 += Bc) {
        int bc = (B - b0 < Bc) ? (B - b0) : Bc;
        char* xc2 = wsb + off;
        float* part = (float*)(xc2 + (size_t)Bc * 409600);
        conv1_kernel<<<bc, 256, 0, stream>>>(images, wT1, conv1_b, xc2, b0);
        int Mtiles = (bc * 36 + 63) / 64;
        gemm_kernel<<<Mtiles * 4, 256, 0, stream>>>(xc2, wpk, part, bc);
        int items = bc * 1152;
        prim2u_kernel<<<(items + 255) / 256, 256, 0, stream>>>(part, prim_b, u, bc, b0);
    }
    dim3 rg((B + 1) / 2, 10);
    routing_kernel<<<rg, 512, 0, stream>>>(u, W, out, B);
}

// Round 5
// 1447.730 us; speedup vs baseline: 1.0864x; 1.0051x over previous
//
#include <hip/hip_runtime.h>
#include <hip/hip_bf16.h>
#include <cstddef>
#include <cstdint>

typedef __attribute__((ext_vector_type(8))) short v8s;     // 8 bf16 (4 VGPR)
typedef __attribute__((ext_vector_type(16))) float v16f;   // MFMA 32x32 acc

#define GLDS(SRC, DST) __builtin_amdgcn_global_load_lds( \
    (const __attribute__((address_space(1))) void*)(SRC), \
    (__attribute__((address_space(3))) void*)(DST), 16, 0, 0)

// RNE fp32 -> bf16 split: x ~= hi + lo, |x - hi - lo| <~ 2^-18 |x|
__device__ __forceinline__ void bf16split(float x, unsigned short& h, unsigned short& l) {
    union { float f; unsigned u; } a; a.f = x;
    unsigned r = a.u + 0x7fff + ((a.u >> 16) & 1);
    h = (unsigned short)(r >> 16);
    union { unsigned u; float f; } hb; hb.u = (unsigned)h << 16;
    union { float f; unsigned u; } b; b.f = x - hb.f;
    unsigned r2 = b.u + 0x7fff + ((b.u >> 16) & 1);
    l = (unsigned short)(r2 >> 16);
}

// ---------------------------------------------------------------------------
// prep: wT1[k*256+oc] = conv1_w[oc*81+k]  (fp32, for conv1)
//       wpk: 648 slabs (g 0..7, k 0..80) of 32 KB, GLDS-linear pre-swizzled:
//       byte D: R=D>>9, off9=(D&511)^((R&31)<<4), h=off9>>7, pl=(off9>>6)&1,
//       icb=off9&63 -> ch=64h+R, ic=g*32+icb/2, plane pl of split(pw[ch][ic][k]).
// grid 5184*256 == 648 slabs * 2048 quads exactly; thread = one 16-B quad.
// ---------------------------------------------------------------------------
__global__ __launch_bounds__(256) void prep_kernel(
    const float* __restrict__ cw, const float* __restrict__ pw,
    float* __restrict__ wT1, char* __restrict__ wpk)
{
    int idx = blockIdx.x * 256 + threadIdx.x;
    if (idx < 81 * 256) {
        int k = idx >> 8, oc = idx & 255;
        wT1[idx] = cw[oc * 81 + k];
    }
    int Q = idx & 2047;
    int slab = idx >> 11;                 // 0..647
    int D = Q << 4;
    int R = D >> 9;                       // 0..63
    int off9 = (D & 511) ^ ((R & 31) << 4);
    int h = off9 >> 7, pl = (off9 >> 6) & 1, icb0 = off9 & 63;
    int ch = h * 64 + R;
    int g = slab / 81, k = slab - g * 81;
    int ic0 = g * 32 + (icb0 >> 1);
    const float* src = pw + ((size_t)ch * 256 + ic0) * 81 + k;
    v8s ov;
#pragma unroll
    for (int j = 0; j < 8; ++j) {
        unsigned short hh, ll; bf16split(src[(size_t)j * 81], hh, ll);
        ov[j] = (short)(pl ? ll : hh);
    }
    *(v8s*)(wpk + (size_t)slab * 32768 + D) = ov;
}

// ---------------------------------------------------------------------------
// conv1: [B,1,28,28] -> xc2 rows [bc*400] of 1024 B: [hi 256 bf16][lo 256 bf16]
// ---------------------------------------------------------------------------
__global__ __launch_bounds__(256) void conv1_kernel(
    const float* __restrict__ img,   // [B][784]
    const float* __restrict__ wT1,   // [81][256]
    const float* __restrict__ bias,  // [256]
    char* __restrict__ xc2,          // [bc][400][1024 B]
    int b0)
{
    const int bl = blockIdx.x;
    const int oc = threadIdx.x;
    __shared__ float im[784];
    const float* ib = img + (size_t)(b0 + bl) * 784;
    for (int e = oc; e < 784; e += 256) im[e] = ib[e];
    float w[81];
#pragma unroll
    for (int k = 0; k < 81; ++k) w[k] = wT1[k * 256 + oc];
    float bv = bias[oc];
    __syncthreads();
    char* ob = xc2 + (size_t)bl * 409600;
    for (int oy = 0; oy < 20; ++oy) {
        for (int ox = 0; ox < 20; ++ox) {
            float a = bv;
#pragma unroll
            for (int ky = 0; ky < 9; ++ky)
#pragma unroll
                for (int kx = 0; kx < 9; ++kx)
                    a = fmaf(w[ky * 9 + kx], im[(oy + ky) * 28 + ox + kx], a);
            a = fmaxf(a, 0.f);
            unsigned short h, l; bf16split(a, h, l);
            char* rp = ob + (size_t)(oy * 20 + ox) * 1024;
            *(unsigned short*)(rp + oc * 2) = h;
            *(unsigned short*)(rp + 512 + oc * 2) = l;
        }
    }
}

// ---------------------------------------------------------------------------
// primary conv implicit GEMM, split-bf16 (3 products), split-K x8 (g = id&7,
// 32 ic each -> 81 steps of K=32). BM=128 x BN=256, 8 waves (wm = w&1 64 rows,
// wn = w>>1 64 ch), wave-tile 64x64 (2x2 frags of 32x32x16), dbuf.
// LDS rows of 512 B hold 4 logical rows (elem = 64h+R for B, 32h+R for A),
// XOR-swizzled over 32 16-B slots -> all MFMA reads 2-way (free).
// A: 32 R x 512 = 16 KB; B: 64 R x 512 = 32 KB; x2 buffers = 96 KB.
// ---------------------------------------------------------------------------
__global__ __launch_bounds__(512, 2) void gemm_kernel(
    const char* __restrict__ xc2,   // [bc][400][1024 B]
    const char* __restrict__ wpk,   // [648 slabs][32 KB]
    float* __restrict__ part,       // [8][M][256]
    int M)
{
    __shared__ __align__(128) char As[2][16384];
    __shared__ __align__(128) char Bs[2][32768];
    const int tid = threadIdx.x;
    const int w = tid >> 6, lane = tid & 63;
    const int wm = w & 1, wn = w >> 1;
    const int col = lane & 31, kg = lane >> 5;
    const int id = blockIdx.x;
    const int g = id & 7;
    const int m0 = (id >> 3) * 128;

    // A-gather per-lane constants (2 issues of 1 KB per wave)
    int pbase[2], asrc[2];
#pragma unroll
    for (int i = 0; i < 2; ++i) {
        int d = (w * 2 + i) * 1024 + lane * 16;   // 0..16383
        int R = d >> 9;                            // 0..31
        int off9 = (d & 511) ^ ((R & 31) << 4);
        int h = off9 >> 7, pl = (off9 >> 6) & 1, w32 = off9 & 63;
        int m = m0 + 32 * h + R;
        if (m >= M) m = M - 1;
        int b = m / 36, s6 = m - b * 36;
        pbase[i] = b * 400 + (s6 / 6) * 40 + (s6 % 6) * 2;
        asrc[i] = pl * 512 + g * 64 + w32;
    }
    const char* wg = wpk + (size_t)g * 81 * 32768;

    v16f acc[2][2];
#pragma unroll
    for (int i = 0; i < 2; ++i)
#pragma unroll
        for (int j = 0; j < 2; ++j)
#pragma unroll
            for (int e = 0; e < 16; ++e) acc[i][j][e] = 0.f;

    // prologue: stage k=0 into buffer 0
#pragma unroll
    for (int i = 0; i < 2; ++i)
        GLDS(xc2 + (size_t)pbase[i] * 1024 + asrc[i], &As[0][(w * 2 + i) * 1024]);
#pragma unroll
    for (int i = 0; i < 4; ++i)
        GLDS(wg + (w * 4 + i) * 1024 + lane * 16, &Bs[0][(w * 4 + i) * 1024]);
    __syncthreads();

    const int xc = col << 4;
    for (int k = 0; k < 81; ++k) {
        const int cur = k & 1;
        if (k < 80) {
            const int kn = k + 1;
            const int koff = (kn / 9) * 20 + (kn % 9);
#pragma unroll
            for (int i = 0; i < 2; ++i)
                GLDS(xc2 + (size_t)(pbase[i] + koff) * 1024 + asrc[i],
                     &As[cur ^ 1][(w * 2 + i) * 1024]);
            const char* bs = wg + (size_t)kn * 32768;
#pragma unroll
            for (int i = 0; i < 4; ++i)
                GLDS(bs + (w * 4 + i) * 1024 + lane * 16,
                     &Bs[cur ^ 1][(w * 4 + i) * 1024]);
        }
        const char* Ab = &As[cur][0];
        const char* Bb = &Bs[cur][0];
#pragma unroll
        for (int s = 0; s < 2; ++s) {
            const int vb = s * 32 + kg * 16;
            v8s Ah[2], Al[2];
#pragma unroll
            for (int fm = 0; fm < 2; ++fm) {
                const int ho = (wm * 2 + fm) * 128;
                Ah[fm] = *(const v8s*)(Ab + col * 512 + ((ho + vb) ^ xc));
                Al[fm] = *(const v8s*)(Ab + col * 512 + ((ho + 64 + vb) ^ xc));
            }
#pragma unroll
            for (int fn = 0; fn < 2; ++fn) {
                const char* bp = Bb + (fn * 32 + col) * 512;
                v8s Bh = *(const v8s*)(bp + ((wn * 128 + vb) ^ xc));
                v8s Bl = *(const v8s*)(bp + ((wn * 128 + 64 + vb) ^ xc));
#pragma unroll
                for (int fm = 0; fm < 2; ++fm) {
                    acc[fm][fn] = __builtin_amdgcn_mfma_f32_32x32x16_bf16(Al[fm], Bh, acc[fm][fn], 0, 0, 0);
                    acc[fm][fn] = __builtin_amdgcn_mfma_f32_32x32x16_bf16(Ah[fm], Bl, acc[fm][fn], 0, 0, 0);
                    acc[fm][fn] = __builtin_amdgcn_mfma_f32_32x32x16_bf16(Ah[fm], Bh, acc[fm][fn], 0, 0, 0);
                }
            }
        }
        __syncthreads();
    }

    // store C partials: part[g][m][ch]
    float* pg = part + (size_t)g * M * 256;
#pragma unroll
    for (int fm = 0; fm < 2; ++fm)
#pragma unroll
        for (int fn = 0; fn < 2; ++fn) {
            int ch = wn * 64 + fn * 32 + col;
#pragma unroll
            for (int rg = 0; rg < 16; ++rg) {
                int row = (rg & 3) + 8 * (rg >> 2) + 4 * kg;
                int m = m0 + wm * 64 + fm * 32 + row;
                if (m < M) pg[(size_t)m * 256 + ch] = acc[fm][fn][rg];
            }
        }
}

// ---------------------------------------------------------------------------
// partials (8) -> +bias -> regroup -> squash -> u [B][1152][8]
// block = 64 m-rows staged in LDS via coalesced float4 reads.
// ---------------------------------------------------------------------------
__global__ __launch_bounds__(256) void prim2u_kernel(
    const float* __restrict__ part, const float* __restrict__ pb,
    float* __restrict__ u, int M, int b0)
{
    __shared__ float p[64 * 256];    // 64 KB
    __shared__ float bsh[256];
    const int tid = threadIdx.x;
    const int rows0 = blockIdx.x * 64;
    bsh[tid] = pb[tid];
#pragma unroll
    for (int j = 0; j < 16; ++j) {
        int e4 = j * 256 + tid;
        int row = e4 >> 6, c4 = (e4 & 63) << 2;
        int rr = rows0 + row; if (rr >= M) rr = M - 1;
        float4 a = make_float4(0.f, 0.f, 0.f, 0.f);
#pragma unroll
        for (int g = 0; g < 8; ++g) {
            float4 v = *(const float4*)(part + ((size_t)g * M + rr) * 256 + c4);
            a.x += v.x; a.y += v.y; a.z += v.z; a.w += v.w;
        }
        *(float4*)&p[row * 256 + c4] = a;
    }
    __syncthreads();
#pragma unroll
    for (int j = 0; j < 8; ++j) {
        int nt = j * 256 + tid;
        int row = nt >> 5, cc = nt & 31;
        int m = rows0 + row;
        if (m >= M) continue;
        int b = m / 36, s = m - b * 36;
        float p8[8]; float sn = 0.f;
#pragma unroll
        for (int d = 0; d < 8; ++d) {
            float v = p[row * 256 + d * 32 + cc] + bsh[d * 32 + cc];
            p8[d] = v; sn += v * v;
        }
        float fac = sqrtf(sn) / (1.0f + sn);
        float4 o0, o1;
        o0.x = fac * p8[0]; o0.y = fac * p8[1]; o0.z = fac * p8[2]; o0.w = fac * p8[3];
        o1.x = fac * p8[4]; o1.y = fac * p8[5]; o1.z = fac * p8[6]; o1.w = fac * p8[7];
        float* up = u + ((size_t)(b0 + b) * 1152 + cc * 36 + s) * 8;
        *(float4*)up = o0;
        *(float4*)(up + 4) = o1;
    }
}

// ---------------------------------------------------------------------------
// routing: one block per (b-pair, c), 512 thr. u_hat TRANSPOSED in LDS
// ([16][1152] per image -> all row loops are lane-consecutive, conflict-free).
// Waves 0-3 image 0, waves 4-7 image 1.
// ---------------------------------------------------------------------------
__global__ __launch_bounds__(512) void routing_kernel(
    const float* __restrict__ u,   // [B][1152][8]
    const float* __restrict__ W,   // [10][1152][8][16]
    float* __restrict__ out,       // [B][10][16]
    int B)
{
    const int b0 = blockIdx.x * 2;
    const int c = blockIdx.y;
    const int tid = threadIdx.x;
    __shared__ float uht[2][16][1152];    // 147456 B
    __shared__ float bijs[2][1152];       // 9216 B
    __shared__ float red[2][4 * 17];
    __shared__ float sred[2][17];
    __shared__ float mred[2][4];

    const float* __restrict__ Wc = W + (size_t)c * (1152 * 128);
    const int b1 = (b0 + 1 < B) ? b0 + 1 : b0;
    const float* __restrict__ ub0 = u + (size_t)b0 * 9216;
    const float* __restrict__ ub1 = u + (size_t)b1 * 9216;

    for (int n = tid; n < 1152; n += 512) {
        const float4* p0 = (const float4*)(ub0 + n * 8);
        const float4* p1 = (const float4*)(ub1 + n * 8);
        float4 a0 = p0[0], a1 = p0[1], c0 = p1[0], c1 = p1[1];
        float uu0[8] = {a0.x, a0.y, a0.z, a0.w, a1.x, a1.y, a1.z, a1.w};
        float uu1[8] = {c0.x, c0.y, c0.z, c0.w, c1.x, c1.y, c1.z, c1.w};
        float acc0[16], acc1[16];
#pragma unroll
        for (int o = 0; o < 16; ++o) { acc0[o] = 0.f; acc1[o] = 0.f; }
        const float* wn = Wc + n * 128;
#pragma unroll
        for (int i = 0; i < 8; ++i)
#pragma unroll
            for (int o = 0; o < 16; ++o) {
                float wv = wn[i * 16 + o];
                acc0[o] = fmaf(uu0[i], wv, acc0[o]);
                acc1[o] = fmaf(uu1[i], wv, acc1[o]);
            }
#pragma unroll
        for (int o = 0; o < 16; ++o) { uht[0][o][n] = acc0[o]; uht[1][o][n] = acc1[o]; }
        bijs[0][n] = 0.f; bijs[1][n] = 0.f;
    }
    __syncthreads();

    const int img = tid >> 8, t = tid & 255;
    const int wid = t >> 6, lane = t & 63;
    const float* __restrict__ UHT = &uht[img][0][0];
    float* __restrict__ bij = bijs[img];
    float* __restrict__ redi = red[img];
    float* __restrict__ sredi = sred[img];
    float* __restrict__ mredi = mred[img];

    float fac = 0.f, inv = 0.f;
    for (int it = 0; it < 3; ++it) {
        float m = -3.4e38f;
        for (int n = t; n < 1152; n += 256) m = fmaxf(m, bij[n]);
#pragma unroll
        for (int off = 32; off > 0; off >>= 1) m = fmaxf(m, __shfl_down(m, off));
        if (lane == 0) mredi[wid] = m;
        __syncthreads();
        float M = fmaxf(fmaxf(mredi[0], mredi[1]), fmaxf(mredi[2], mredi[3]));
        float se = 0.f;
        float sp[16];
#pragma unroll
        for (int o = 0; o < 16; ++o) sp[o] = 0.f;
        for (int n = t; n < 1152; n += 256) {
            float e = expf(bij[n] - M);
            se += e;
#pragma unroll
            for (int o = 0; o < 16; ++o) sp[o] = fmaf(e, UHT[o * 1152 + n], sp[o]);
        }
#pragma unroll
        for (int o = 0; o < 16; ++o)
#pragma unroll
            for (int off = 32; off > 0; off >>= 1) sp[o] += __shfl_down(sp[o], off);
#pragma unroll
        for (int off = 32; off > 0; off >>= 1) se += __shfl_down(se, off);
        if (lane == 0) {
#pragma unroll
            for (int o = 0; o < 16; ++o) redi[wid * 17 + o] = sp[o];
            redi[wid * 17 + 16] = se;
        }
        __syncthreads();
        if (t < 17)
            sredi[t] = redi[t] + redi[17 + t] + redi[34 + t] + redi[51 + t];
        __syncthreads();
        inv = 1.0f / sredi[16];
        float sn = 0.f;
        float sj[16];
#pragma unroll
        for (int o = 0; o < 16; ++o) { sj[o] = sredi[o] * inv; sn = fmaf(sj[o], sj[o], sn); }
        fac = sqrtf(sn) / (1.0f + sn);
        if (it < 2) {
            float v[16];
#pragma unroll
            for (int o = 0; o < 16; ++o) v[o] = fac * sj[o];
            for (int n = t; n < 1152; n += 256) {
                float a = 0.f;
#pragma unroll
                for (int o = 0; o < 16; ++o) a = fmaf(UHT[o * 1152 + n], v[o], a);
                bij[n] += a;
            }
        }
        __syncthreads();
    }
    if (t < 16 && b0 + img < B)
        out[((size_t)(b0 + img) * 10 + c) * 16 + t] = fac * (sredi[t] * inv);
}

// ---------------------------------------------------------------------------
extern "C" void kernel_launch(void* const* d_in, const int* in_sizes, int n_in,
                              void* d_out, int out_size, void* d_ws, size_t ws_size,
                              hipStream_t stream) {
    const float* images  = (const float*)d_in[0];
    const float* conv1_w = (const float*)d_in[1];
    const float* conv1_b = (const float*)d_in[2];
    const float* prim_w  = (const float*)d_in[3];
    const float* prim_b  = (const float*)d_in[4];
    const float* W       = (const float*)d_in[5];
    float* out = (float*)d_out;

    const int B = in_sizes[0] / 784;

    char* wsb = (char*)d_ws;
    float* u = (float*)wsb;
    size_t off = (size_t)B * 1152 * 8 * 4;
    float* wT1 = (float*)(wsb + off);
    off += 81 * 256 * 4;
    off = (off + 1023) & ~(size_t)1023;
    char* wpk = wsb + off;
    off += (size_t)648 * 32768;                  // 21.2 MB
    size_t rem = (ws_size > off) ? ws_size - off : 0;
    const size_t perimg = 409600 + 294912;       // xc2 + 8 partial planes
    int Bc = (int)(rem / perimg);
    if (Bc > B) Bc = B;
    if (Bc >= 32) Bc &= ~31;                     // multiple of 32 -> M % 128 == 0
    if (Bc < 1) Bc = 1;

    prep_kernel<<<5184, 256, 0, stream>>>(conv1_w, prim_w, wT1, wpk);

    for (int b0 = 0; b0 < B; b0 += Bc) {
        int bc = (B - b0 < Bc) ? (B - b0) : Bc;
        char* xc2 = wsb + off;
        float* part = (float*)(xc2 + (size_t)Bc * 409600);
        conv1_kernel<<<bc, 256, 0, stream>>>(images, wT1, conv1_b, xc2, b0);
        int M = bc * 36;
        int Mtiles = (M + 127) / 128;
        gemm_kernel<<<Mtiles * 8, 512, 0, stream>>>(xc2, wpk, part, M);
        prim2u_kernel<<<(M + 63) / 64, 256, 0, stream>>>(part, prim_b, u, M, b0);
    }
    dim3 rg((B + 1) / 2, 10);
    routing_kernel<<<rg, 512, 0, stream>>>(u, W, out, B);
}

// Round 6
// 1185.882 us; speedup vs baseline: 1.3263x; 1.2208x over previous
//
#include <hip/hip_runtime.h>
#include <hip/hip_bf16.h>
#include <cstddef>
#include <cstdint>

typedef __attribute__((ext_vector_type(8))) short v8s;     // 8 bf16 (4 VGPR)
typedef __attribute__((ext_vector_type(16))) float v16f;   // MFMA 32x32 acc

#define GLDS(SRC, DST) __builtin_amdgcn_global_load_lds( \
    (const __attribute__((address_space(1))) void*)(SRC), \
    (__attribute__((address_space(3))) void*)(DST), 16, 0, 0)

#define WAIT_VM6() asm volatile("s_waitcnt vmcnt(6)" ::: "memory")
#define WAIT_VM0() asm volatile("s_waitcnt vmcnt(0)" ::: "memory")
#define SCHED0()   __builtin_amdgcn_sched_barrier(0)

// RNE fp32 -> bf16 split: x ~= hi + lo, |x - hi - lo| <~ 2^-18 |x|
__device__ __forceinline__ void bf16split(float x, unsigned short& h, unsigned short& l) {
    union { float f; unsigned u; } a; a.f = x;
    unsigned r = a.u + 0x7fff + ((a.u >> 16) & 1);
    h = (unsigned short)(r >> 16);
    union { unsigned u; float f; } hb; hb.u = (unsigned)h << 16;
    union { float f; unsigned u; } b; b.f = x - hb.f;
    unsigned r2 = b.u + 0x7fff + ((b.u >> 16) & 1);
    l = (unsigned short)(r2 >> 16);
}

// ---------------------------------------------------------------------------
// prep: wT1[k*256+oc] = conv1_w[oc*81+k]  (fp32, for conv1)
//       wpk: 648 slabs (g 0..7, k 0..80) of 32 KB, GLDS-linear pre-swizzled:
//       byte D: R=D>>9, off9=(D&511)^((R&31)<<4), h=off9>>7, pl=(off9>>6)&1,
//       icb=off9&63 -> ch=64h+R, ic=g*32+icb/2, plane pl of split(pw[ch][ic][k]).
// ---------------------------------------------------------------------------
__global__ __launch_bounds__(256) void prep_kernel(
    const float* __restrict__ cw, const float* __restrict__ pw,
    float* __restrict__ wT1, char* __restrict__ wpk)
{
    int idx = blockIdx.x * 256 + threadIdx.x;
    if (idx < 81 * 256) {
        int k = idx >> 8, oc = idx & 255;
        wT1[idx] = cw[oc * 81 + k];
    }
    int Q = idx & 2047;
    int slab = idx >> 11;                 // 0..647
    int D = Q << 4;
    int R = D >> 9;                       // 0..63
    int off9 = (D & 511) ^ ((R & 31) << 4);
    int h = off9 >> 7, pl = (off9 >> 6) & 1, icb0 = off9 & 63;
    int ch = h * 64 + R;
    int g = slab / 81, k = slab - g * 81;
    int ic0 = g * 32 + (icb0 >> 1);
    const float* src = pw + ((size_t)ch * 256 + ic0) * 81 + k;
    v8s ov;
#pragma unroll
    for (int j = 0; j < 8; ++j) {
        unsigned short hh, ll; bf16split(src[(size_t)j * 81], hh, ll);
        ov[j] = (short)(pl ? ll : hh);
    }
    *(v8s*)(wpk + (size_t)slab * 32768 + D) = ov;
}

// ---------------------------------------------------------------------------
// conv1 (register-tiled): [B,1,28,28] -> xc2 rows of 1024 B [hi 256][lo 256]
// Each (oy,ky): image row segment read once via float4 -> 6.4x fewer LDS ops,
// VALU-bound (~54 us chip floor).
// ---------------------------------------------------------------------------
__global__ __launch_bounds__(256) void conv1_kernel(
    const float* __restrict__ img,   // [B][784]
    const float* __restrict__ wT1,   // [81][256]
    const float* __restrict__ bias,  // [256]
    char* __restrict__ xc2,          // [bc][400][1024 B]
    int b0)
{
    const int bl = blockIdx.x;
    const int oc = threadIdx.x;
    __shared__ __align__(16) float im[784];
    const float* ib = img + (size_t)(b0 + bl) * 784;
    for (int e = oc; e < 784; e += 256) im[e] = ib[e];
    float w[81];
#pragma unroll
    for (int k = 0; k < 81; ++k) w[k] = wT1[k * 256 + oc];
    float bv = bias[oc];
    __syncthreads();
    char* ob = xc2 + (size_t)bl * 409600;
    for (int oy = 0; oy < 20; ++oy) {
        float a[20];
#pragma unroll
        for (int ox = 0; ox < 20; ++ox) a[ox] = bv;
        for (int ky = 0; ky < 9; ++ky) {
            const float* rp = &im[(oy + ky) * 28];
            float r[28];
#pragma unroll
            for (int q = 0; q < 7; ++q) {
                float4 v4 = *(const float4*)(rp + q * 4);
                r[q * 4] = v4.x; r[q * 4 + 1] = v4.y;
                r[q * 4 + 2] = v4.z; r[q * 4 + 3] = v4.w;
            }
#pragma unroll
            for (int kx = 0; kx < 9; ++kx) {
                float wv = w[ky * 9 + kx];
#pragma unroll
                for (int ox = 0; ox < 20; ++ox)
                    a[ox] = fmaf(wv, r[ox + kx], a[ox]);
            }
        }
#pragma unroll
        for (int ox = 0; ox < 20; ++ox) {
            float av = fmaxf(a[ox], 0.f);
            unsigned short h, l; bf16split(av, h, l);
            char* rp2 = ob + (size_t)(oy * 20 + ox) * 1024;
            *(unsigned short*)(rp2 + oc * 2) = h;
            *(unsigned short*)(rp2 + 512 + oc * 2) = l;
        }
    }
}

// ---------------------------------------------------------------------------
// primary conv implicit GEMM, split-bf16 (3 products), split-K x8 (g = id&7,
// 32 ic -> 81 steps of K=32). BM=128 x BN=256, 8 waves, wave-tile 64x64.
// TRIPLE-buffered with counted s_waitcnt vmcnt(6) + raw s_barrier (T4):
// loads for step k+1 stay in flight across the step-k barrier; never drained
// to 0 in the main loop. setprio(1) around the 24-MFMA cluster (T5).
// LDS rows of 512 B hold 4 logical rows, XOR over 32 16-B slots -> all MFMA
// reads 2-way (free).  3 x (A 16 KB + B 32 KB) = 144 KB.
// ---------------------------------------------------------------------------
__global__ __launch_bounds__(512, 1) void gemm_kernel(
    const char* __restrict__ xc2,   // [bc][400][1024 B]
    const char* __restrict__ wpk,   // [648 slabs][32 KB]
    float* __restrict__ part,       // [8][M][256]
    int M)
{
    __shared__ __align__(128) char As[3][16384];
    __shared__ __align__(128) char Bs[3][32768];
    const int tid = threadIdx.x;
    const int w = tid >> 6, lane = tid & 63;
    const int wm = w & 1, wn = w >> 1;
    const int col = lane & 31, kg = lane >> 5;
    const int id = blockIdx.x;
    const int g = id & 7;
    const int m0 = (id >> 3) * 128;

    // A-gather per-lane constants (2 issues of 1 KB per wave)
    int pbase[2], asrc[2];
#pragma unroll
    for (int i = 0; i < 2; ++i) {
        int d = (w * 2 + i) * 1024 + lane * 16;   // 0..16383
        int R = d >> 9;                            // 0..31
        int off9 = (d & 511) ^ ((R & 31) << 4);
        int h = off9 >> 7, pl = (off9 >> 6) & 1, w32 = off9 & 63;
        int m = m0 + 32 * h + R;
        if (m >= M) m = M - 1;
        int b = m / 36, s6 = m - b * 36;
        pbase[i] = b * 400 + (s6 / 6) * 40 + (s6 % 6) * 2;
        asrc[i] = pl * 512 + g * 64 + w32;
    }
    const char* wg = wpk + (size_t)g * 81 * 32768;

    v16f acc[2][2];
#pragma unroll
    for (int i = 0; i < 2; ++i)
#pragma unroll
        for (int j = 0; j < 2; ++j)
#pragma unroll
            for (int e = 0; e < 16; ++e) acc[i][j][e] = 0.f;

    // stage step kk into buffer nb (6 GLDS per wave: 2 A + 4 B)
    auto stage = [&](int nb, int kk) {
        const int koff = (kk / 9) * 20 + (kk % 9);
#pragma unroll
        for (int i = 0; i < 2; ++i)
            GLDS(xc2 + (size_t)(pbase[i] + koff) * 1024 + asrc[i],
                 &As[nb][(w * 2 + i) * 1024]);
        const char* bs = wg + (size_t)kk * 32768;
#pragma unroll
        for (int i = 0; i < 4; ++i)
            GLDS(bs + (w * 4 + i) * 1024 + lane * 16,
                 &Bs[nb][(w * 4 + i) * 1024]);
    };

    // prologue: fill buffers 0 and 1
    stage(0, 0);
    stage(1, 1);
    WAIT_VM6(); SCHED0();
    __builtin_amdgcn_s_barrier(); SCHED0();

    const int xc = col << 4;
    for (int k = 0; k < 81; ++k) {
        const int cur = k % 3;
        if (k + 2 < 81) stage((k + 2) % 3, k + 2);

        const char* Ab = &As[cur][0];
        const char* Bb = &Bs[cur][0];
        // hoist all 16 fragment reads, then one MFMA cluster
        v8s Ah[2][2], Al[2][2], Bh[2][2], Bl[2][2];   // [s][f]
#pragma unroll
        for (int s = 0; s < 2; ++s) {
            const int vb = s * 32 + kg * 16;
#pragma unroll
            for (int fm = 0; fm < 2; ++fm) {
                const int ho = (wm * 2 + fm) * 128;
                Ah[s][fm] = *(const v8s*)(Ab + col * 512 + ((ho + vb) ^ xc));
                Al[s][fm] = *(const v8s*)(Ab + col * 512 + ((ho + 64 + vb) ^ xc));
            }
#pragma unroll
            for (int fn = 0; fn < 2; ++fn) {
                const char* bp = Bb + (fn * 32 + col) * 512;
                Bh[s][fn] = *(const v8s*)(bp + ((wn * 128 + vb) ^ xc));
                Bl[s][fn] = *(const v8s*)(bp + ((wn * 128 + 64 + vb) ^ xc));
            }
        }
        __builtin_amdgcn_s_setprio(1);
#pragma unroll
        for (int s = 0; s < 2; ++s)
#pragma unroll
            for (int fn = 0; fn < 2; ++fn)
#pragma unroll
                for (int fm = 0; fm < 2; ++fm) {
                    acc[fm][fn] = __builtin_amdgcn_mfma_f32_32x32x16_bf16(Al[s][fm], Bh[s][fn], acc[fm][fn], 0, 0, 0);
                    acc[fm][fn] = __builtin_amdgcn_mfma_f32_32x32x16_bf16(Ah[s][fm], Bl[s][fn], acc[fm][fn], 0, 0, 0);
                    acc[fm][fn] = __builtin_amdgcn_mfma_f32_32x32x16_bf16(Ah[s][fm], Bh[s][fn], acc[fm][fn], 0, 0, 0);
                }
        __builtin_amdgcn_s_setprio(0);

        if (k < 80) {
            if (k < 79) { WAIT_VM6(); } else { WAIT_VM0(); }
            SCHED0();
            __builtin_amdgcn_s_barrier();
            SCHED0();
        }
    }

    // store C partials: part[g][m][ch]
    float* pg = part + (size_t)g * M * 256;
#pragma unroll
    for (int fm = 0; fm < 2; ++fm)
#pragma unroll
        for (int fn = 0; fn < 2; ++fn) {
            int ch = wn * 64 + fn * 32 + col;
#pragma unroll
            for (int rg = 0; rg < 16; ++rg) {
                int row = (rg & 3) + 8 * (rg >> 2) + 4 * kg;
                int m = m0 + wm * 64 + fm * 32 + row;
                if (m < M) pg[(size_t)m * 256 + ch] = acc[fm][fn][rg];
            }
        }
}

// ---------------------------------------------------------------------------
// partials (8) -> +bias -> regroup -> squash -> u [B][1152][8]
// ---------------------------------------------------------------------------
__global__ __launch_bounds__(256) void prim2u_kernel(
    const float* __restrict__ part, const float* __restrict__ pb,
    float* __restrict__ u, int M, int b0)
{
    __shared__ float p[64 * 256];    // 64 KB
    __shared__ float bsh[256];
    const int tid = threadIdx.x;
    const int rows0 = blockIdx.x * 64;
    bsh[tid] = pb[tid];
#pragma unroll
    for (int j = 0; j < 16; ++j) {
        int e4 = j * 256 + tid;
        int row = e4 >> 6, c4 = (e4 & 63) << 2;
        int rr = rows0 + row; if (rr >= M) rr = M - 1;
        float4 a = make_float4(0.f, 0.f, 0.f, 0.f);
#pragma unroll
        for (int g = 0; g < 8; ++g) {
            float4 v = *(const float4*)(part + ((size_t)g * M + rr) * 256 + c4);
            a.x += v.x; a.y += v.y; a.z += v.z; a.w += v.w;
        }
        *(float4*)&p[row * 256 + c4] = a;
    }
    __syncthreads();
#pragma unroll
    for (int j = 0; j < 8; ++j) {
        int nt = j * 256 + tid;
        int row = nt >> 5, cc = nt & 31;
        int m = rows0 + row;
        if (m >= M) continue;
        int b = m / 36, s = m - b * 36;
        float p8[8]; float sn = 0.f;
#pragma unroll
        for (int d = 0; d < 8; ++d) {
            float v = p[row * 256 + d * 32 + cc] + bsh[d * 32 + cc];
            p8[d] = v; sn += v * v;
        }
        float fac = sqrtf(sn) / (1.0f + sn);
        float4 o0, o1;
        o0.x = fac * p8[0]; o0.y = fac * p8[1]; o0.z = fac * p8[2]; o0.w = fac * p8[3];
        o1.x = fac * p8[4]; o1.y = fac * p8[5]; o1.z = fac * p8[6]; o1.w = fac * p8[7];
        float* up = u + ((size_t)(b0 + b) * 1152 + cc * 36 + s) * 8;
        *(float4*)up = o0;
        *(float4*)(up + 4) = o1;
    }
}

// ---------------------------------------------------------------------------
// routing: one block per (b-pair, c), 512 thr. u_hat TRANSPOSED in LDS
// ([16][1152] per image -> all row loops lane-consecutive, conflict-free).
// Waves 0-3 image 0, waves 4-7 image 1.
// ---------------------------------------------------------------------------
__global__ __launch_bounds__(512) void routing_kernel(
    const float* __restrict__ u,   // [B][1152][8]
    const float* __restrict__ W,   // [10][1152][8][16]
    float* __restrict__ out,       // [B][10][16]
    int B)
{
    const int b0 = blockIdx.x * 2;
    const int c = blockIdx.y;
    const int tid = threadIdx.x;
    __shared__ float uht[2][16][1152];    // 147456 B
    __shared__ float bijs[2][1152];       // 9216 B
    __shared__ float red[2][4 * 17];
    __shared__ float sred[2][17];
    __shared__ float mred[2][4];

    const float* __restrict__ Wc = W + (size_t)c * (1152 * 128);
    const int b1 = (b0 + 1 < B) ? b0 + 1 : b0;
    const float* __restrict__ ub0 = u + (size_t)b0 * 9216;
    const float* __restrict__ ub1 = u + (size_t)b1 * 9216;

    for (int n = tid; n < 1152; n += 512) {
        const float4* p0 = (const float4*)(ub0 + n * 8);
        const float4* p1 = (const float4*)(ub1 + n * 8);
        float4 a0 = p0[0], a1 = p0[1], c0 = p1[0], c1 = p1[1];
        float uu0[8] = {a0.x, a0.y, a0.z, a0.w, a1.x, a1.y, a1.z, a1.w};
        float uu1[8] = {c0.x, c0.y, c0.z, c0.w, c1.x, c1.y, c1.z, c1.w};
        float acc0[16], acc1[16];
#pragma unroll
        for (int o = 0; o < 16; ++o) { acc0[o] = 0.f; acc1[o] = 0.f; }
        const float* wn = Wc + n * 128;
#pragma unroll
        for (int i = 0; i < 8; ++i)
#pragma unroll
            for (int o = 0; o < 16; ++o) {
                float wv = wn[i * 16 + o];
                acc0[o] = fmaf(uu0[i], wv, acc0[o]);
                acc1[o] = fmaf(uu1[i], wv, acc1[o]);
            }
#pragma unroll
        for (int o = 0; o < 16; ++o) { uht[0][o][n] = acc0[o]; uht[1][o][n] = acc1[o]; }
        bijs[0][n] = 0.f; bijs[1][n] = 0.f;
    }
    __syncthreads();

    const int img = tid >> 8, t = tid & 255;
    const int wid = t >> 6, lane = t & 63;
    const float* __restrict__ UHT = &uht[img][0][0];
    float* __restrict__ bij = bijs[img];
    float* __restrict__ redi = red[img];
    float* __restrict__ sredi = sred[img];
    float* __restrict__ mredi = mred[img];

    float fac = 0.f, inv = 0.f;
    for (int it = 0; it < 3; ++it) {
        float m = -3.4e38f;
        for (int n = t; n < 1152; n += 256) m = fmaxf(m, bij[n]);
#pragma unroll
        for (int off = 32; off > 0; off >>= 1) m = fmaxf(m, __shfl_down(m, off));
        if (lane == 0) mredi[wid] = m;
        __syncthreads();
        float M = fmaxf(fmaxf(mredi[0], mredi[1]), fmaxf(mredi[2], mredi[3]));
        float se = 0.f;
        float sp[16];
#pragma unroll
        for (int o = 0; o < 16; ++o) sp[o] = 0.f;
        for (int n = t; n < 1152; n += 256) {
            float e = expf(bij[n] - M);
            se += e;
#pragma unroll
            for (int o = 0; o < 16; ++o) sp[o] = fmaf(e, UHT[o * 1152 + n], sp[o]);
        }
#pragma unroll
        for (int o = 0; o < 16; ++o)
#pragma unroll
            for (int off = 32; off > 0; off >>= 1) sp[o] += __shfl_down(sp[o], off);
#pragma unroll
        for (int off = 32; off > 0; off >>= 1) se += __shfl_down(se, off);
        if (lane == 0) {
#pragma unroll
            for (int o = 0; o < 16; ++o) redi[wid * 17 + o] = sp[o];
            redi[wid * 17 + 16] = se;
        }
        __syncthreads();
        if (t < 17)
            sredi[t] = redi[t] + redi[17 + t] + redi[34 + t] + redi[51 + t];
        __syncthreads();
        inv = 1.0f / sredi[16];
        float sn = 0.f;
        float sj[16];
#pragma unroll
        for (int o = 0; o < 16; ++o) { sj[o] = sredi[o] * inv; sn = fmaf(sj[o], sj[o], sn); }
        fac = sqrtf(sn) / (1.0f + sn);
        if (it < 2) {
            float v[16];
#pragma unroll
            for (int o = 0; o < 16; ++o) v[o] = fac * sj[o];
            for (int n = t; n < 1152; n += 256) {
                float a = 0.f;
#pragma unroll
                for (int o = 0; o < 16; ++o) a = fmaf(UHT[o * 1152 + n], v[o], a);
                bij[n] += a;
            }
        }
        __syncthreads();
    }
    if (t < 16 && b0 + img < B)
        out[((size_t)(b0 + img) * 10 + c) * 16 + t] = fac * (sredi[t] * inv);
}

// ---------------------------------------------------------------------------
extern "C" void kernel_launch(void* const* d_in, const int* in_sizes, int n_in,
                              void* d_out, int out_size, void* d_ws, size_t ws_size,
                              hipStream_t stream) {
    const float* images  = (const float*)d_in[0];
    const float* conv1_w = (const float*)d_in[1];
    const float* conv1_b = (const float*)d_in[2];
    const float* prim_w  = (const float*)d_in[3];
    const float* prim_b  = (const float*)d_in[4];
    const float* W       = (const float*)d_in[5];
    float* out = (float*)d_out;

    const int B = in_sizes[0] / 784;

    char* wsb = (char*)d_ws;
    float* u = (float*)wsb;
    size_t off = (size_t)B * 1152 * 8 * 4;
    float* wT1 = (float*)(wsb + off);
    off += 81 * 256 * 4;
    off = (off + 1023) & ~(size_t)1023;
    char* wpk = wsb + off;
    off += (size_t)648 * 32768;                  // 21.2 MB
    size_t rem = (ws_size > off) ? ws_size - off : 0;
    const size_t perimg = 409600 + 294912;       // xc2 + 8 partial planes
    int Bc = (int)(rem / perimg);
    if (Bc > B) Bc = B;
    if (Bc >= 32) Bc &= ~31;                     // multiple of 32 -> M % 128 == 0
    if (Bc < 1) Bc = 1;

    prep_kernel<<<5184, 256, 0, stream>>>(conv1_w, prim_w, wT1, wpk);

    for (int b0 = 0; b0 < B; b0 += Bc) {
        int bc = (B - b0 < Bc) ? (B - b0) : Bc;
        char* xc2 = wsb + off;
        float* part = (float*)(xc2 + (size_t)Bc * 409600);
        conv1_kernel<<<bc, 256, 0, stream>>>(images, wT1, conv1_b, xc2, b0);
        int M = bc * 36;
        int Mtiles = (M + 127) / 128;
        gemm_kernel<<<Mtiles * 8, 512, 0, stream>>>(xc2, wpk, part, M);
        prim2u_kernel<<<(M + 63) / 64, 256, 0, stream>>>(part, prim_b, u, M, b0);
    }
    dim3 rg((B + 1) / 2, 10);
    routing_kernel<<<rg, 512, 0, stream>>>(u, W, out, B);
}